// Round 3
// baseline (133.391 us; speedup 1.0000x reference)
//
#include <hip/hip_runtime.h>

// MyAttention: B=2, T=4096, D=768, DO=256, H=4, DH=64, W2=15
// Structure (R9): cast_w -> gemm_bf16 (A direct global->reg in MFMA fragment
// layout, fp32 cast in-flight; B via global_load_lds dbuf) -> win_attn4.
// R9: GEMM was LDS-BW-bound (~73KB/K-step/block through the 128B/cyc LDS
// pipe). A's LDS round-trip (reg->ds_write->ds_read) removed: the 16x16x32
// A-fragment is per-lane addressable straight from global fp32
// (row m0+wm*32+i*16+fr, k = k0+ks*32+quad*8, 8 consecutive floats).
// Global A bytes unchanged (196KB/block, XCD-L2-resident via chunk swizzle).
// Convert placed AFTER the MFMA cluster so its vmcnt wait hides behind MFMA.
// R7/R8 kept: 2-phase B double-buffer, single syncthreads/K-step, bijective
// XCD-chunk swizzle (520 = 8*65), B k-chunk XOR swizzle for bank-min reads.
#define TPC   4110            // T + 14 (padded seq)
#define MROWS 8220            // B * TPC
#define MTOT  8235            // + 15 pos rows
#define MPAD  8320            // 130 * 64
#define KD    768

typedef __attribute__((ext_vector_type(8))) short short8;
typedef __attribute__((ext_vector_type(4))) float f32x4;

#define LOAD_LDS16(gp, lp)                                                   \
  __builtin_amdgcn_global_load_lds(                                          \
      (const __attribute__((address_space(1))) void*)(gp),                   \
      (__attribute__((address_space(3))) void*)(lp), 16, 0, 0)

__device__ inline unsigned bfr(float x) {
  unsigned u = __float_as_uint(x);
  return (u + 0x7FFFu + ((u >> 16) & 1u)) >> 16;   // RNE fp32->bf16
}
__device__ inline unsigned pack2(float a, float b) {
  return bfr(a) | (bfr(b) << 16);
}
__device__ inline float bflo(unsigned u) { return __uint_as_float(u << 16); }
__device__ inline float bfhi(unsigned u) { return __uint_as_float(u & 0xffff0000u); }

// ---------------------------------------------------------------------------
// Pass 1: cast W only ([Wq;Wv], 512 x 768) to bf16. 192 blocks, ~0.4 us.
__global__ __launch_bounds__(256) void cast_w(
    const float* __restrict__ Wq, const float* __restrict__ Wv,
    ushort* __restrict__ Wbf) {
  int gid = blockIdx.x * 256 + threadIdx.x;      // grid = 512*96/256 exact
  int row = gid / 96, c = (gid - row * 96) * 8;
  const float* src = (row < 256) ? Wq + (size_t)row * KD + c
                                 : Wv + (size_t)(row - 256) * KD + c;
  float4 f0 = *(const float4*)src;
  float4 f1 = *(const float4*)(src + 4);
  uint4 o;
  o.x = pack2(f0.x, f0.y); o.y = pack2(f0.z, f0.w);
  o.z = pack2(f1.x, f1.y); o.w = pack2(f1.z, f1.w);
  *(uint4*)(Wbf + (size_t)row * KD + c) = o;
}

// ---------------------------------------------------------------------------
// Pass 2: C[MPAD][512] = A @ Wbf^T. bf16 MFMA 16x16x32, 64(m) x 128(n) tiles,
// BK=64, 520 blocks. A: per-lane fragment loads from fp32 global (zero-pad +
// pos rows via per-lane pointer predication), cvt->bf16 regs after the MFMA
// cluster. B: global_load_lds width-16 from Wbf into 2x16KB dbuf, k-chunks
// XOR-swizzled by (row&7) so fragment ds_read_b128 stays at bank minimum.
// Grid 1D + bijective XCD-chunk swizzle: each XCD gets ~16 consecutive
// m-tiles x 4 n-strips -> fp32-A re-reads are that XCD's L2 hits.
// bf16 outputs in attention layout q/v [B][H][TPC][64]; pos -> [15][256].
__global__ __launch_bounds__(256) void gemm_bf16(
    const float* __restrict__ inp, const float* __restrict__ pos,
    const ushort* __restrict__ Wbf,
    const float* __restrict__ bq, const float* __restrict__ bv,
    ushort* __restrict__ q_out, ushort* __restrict__ v_out,
    ushort* __restrict__ pos_q, ushort* __restrict__ pos_v) {
  __shared__ ushort Bl[2][128 * 64];   // 2 x 16 KB
  const int tid = threadIdx.x;
  const int wave = tid >> 6, lane = tid & 63;
  const int lin = blockIdx.x;
  const int wg = (lin & 7) * 65 + (lin >> 3);
  const int ns = wg & 3;                // 0..3 (0-1 -> q, 2-3 -> v)
  const int m0 = (wg >> 2) * 64;        // 0..129 m-tiles
  const int wm = wave & 1, wn = wave >> 1;
  const int fr = lane & 15, quad = lane >> 4;

  // A fragment source pointers: one per i (row = m0+wm*32+i*16+fr), offset
  // quad*8 baked in; k-step adds k0 + ks*32. Null -> zero rows (pad / tail).
  const float* agf[2];
  #pragma unroll
  for (int i = 0; i < 2; i++) {
    int m = m0 + wm * 32 + i * 16 + fr;
    const float* s = nullptr;
    if (m < MROWS) {
      int bb = (m >= TPC) ? 1 : 0;
      int t = m - bb * TPC - 7;
      if (t >= 0 && t < 4096)
        s = inp + ((size_t)bb * 4096 + t) * KD + quad * 8;
    } else if (m < MTOT) {
      s = pos + (size_t)(m - MROWS) * KD + quad * 8;
    }
    agf[i] = s;
  }
  const ushort* bg[4];
  #pragma unroll
  for (int i = 0; i < 4; i++) {
    int c = i * 256 + tid, row = c >> 3, kq = c & 7;
    bg[i] = Wbf + (size_t)(ns * 128 + row) * KD + ((kq ^ (row & 7)) * 8);
  }

  f32x4 acc[2][4];
  #pragma unroll
  for (int i = 0; i < 2; i++)
    #pragma unroll
    for (int j = 0; j < 4; j++) acc[i][j] = 0.0f;

  float4 fa[2][2][2];                   // [i][ks][half] in-flight fp32 A
  short8 afr[2][2];                     // [ks][i] current bf16 A fragments

#define A_LOAD(k0)                                                           \
  do {                                                                       \
    _Pragma("unroll")                                                        \
    for (int i = 0; i < 2; i++) {                                            \
      if (agf[i]) {                                                          \
        _Pragma("unroll")                                                    \
        for (int ks = 0; ks < 2; ks++) {                                     \
          fa[i][ks][0] = *(const float4*)(agf[i] + (k0) + ks * 32);          \
          fa[i][ks][1] = *(const float4*)(agf[i] + (k0) + ks * 32 + 4);      \
        }                                                                    \
      } else {                                                               \
        _Pragma("unroll")                                                    \
        for (int ks = 0; ks < 2; ks++) {                                     \
          fa[i][ks][0] = make_float4(0.f, 0.f, 0.f, 0.f);                    \
          fa[i][ks][1] = make_float4(0.f, 0.f, 0.f, 0.f);                    \
        }                                                                    \
      }                                                                      \
    }                                                                        \
  } while (0)

#define A_CVT()                                                              \
  do {                                                                       \
    _Pragma("unroll")                                                        \
    for (int i = 0; i < 2; i++)                                              \
      _Pragma("unroll")                                                      \
      for (int ks = 0; ks < 2; ks++) {                                       \
        uint4 o;                                                             \
        o.x = pack2(fa[i][ks][0].x, fa[i][ks][0].y);                         \
        o.y = pack2(fa[i][ks][0].z, fa[i][ks][0].w);                         \
        o.z = pack2(fa[i][ks][1].x, fa[i][ks][1].y);                         \
        o.w = pack2(fa[i][ks][1].z, fa[i][ks][1].w);                         \
        afr[ks][i] = *(short8*)&o;                                           \
      }                                                                      \
  } while (0)

#define STAGE_B(bsel, k0)                                                    \
  do {                                                                       \
    _Pragma("unroll")                                                        \
    for (int i = 0; i < 4; i++)                                              \
      LOAD_LDS16(bg[i] + (k0), &Bl[bsel][0] + (i * 256 + wave * 64) * 8);    \
  } while (0)

#define COMPUTE(bsel)                                                        \
  do {                                                                       \
    short8 bfrag[2][4];                                                      \
    _Pragma("unroll")                                                        \
    for (int ks = 0; ks < 2; ks++) {                                         \
      const int e = ((ks * 4 + quad) ^ (fr & 7)) * 8;   /* un-swizzle */     \
      _Pragma("unroll")                                                      \
      for (int j = 0; j < 4; j++)                                            \
        bfrag[ks][j] =                                                       \
            *(const short8*)(&Bl[bsel][0] + (wn * 64 + j * 16 + fr) * 64 + e);\
    }                                                                        \
    _Pragma("unroll")                                                        \
    for (int ks = 0; ks < 2; ks++)                                           \
      _Pragma("unroll")                                                      \
      for (int i = 0; i < 2; i++)                                            \
        _Pragma("unroll")                                                    \
        for (int j = 0; j < 4; j++)                                          \
          acc[i][j] = __builtin_amdgcn_mfma_f32_16x16x32_bf16(               \
              afr[ks][i], bfrag[ks][j], acc[i][j], 0, 0, 0);                 \
  } while (0)

  // prologue: A frags for k=0 -> regs; B k=0 -> buf0; drain.
  A_LOAD(0);
  STAGE_B(0, 0);
  A_CVT();
  __syncthreads();
  // steady state: 12 K-steps, 2 per body (compile-time buffer index).
  // Body: issue next A-frag loads + next B gload_lds; MFMA current (afr is
  // ready, B in current buf); convert the landed A loads (vmcnt wait sits
  // behind the MFMA cluster); barrier swaps B buffers (drains B's vmcnt).
  #pragma unroll 1
  for (int k0 = 0; k0 < 640; k0 += 128) {
    A_LOAD(k0 + 64);
    STAGE_B(1, k0 + 64);
    COMPUTE(0);
    A_CVT();
    __syncthreads();
    A_LOAD(k0 + 128);
    STAGE_B(0, k0 + 128);
    COMPUTE(1);
    A_CVT();
    __syncthreads();
  }
  A_LOAD(704);
  STAGE_B(1, 704);
  COMPUTE(0);                   // k = 640
  A_CVT();
  __syncthreads();
  COMPUTE(1);                   // k = 704 (no further stage)

#undef A_LOAD
#undef A_CVT
#undef STAGE_B
#undef COMPUTE

  // epilogue: C/D layout col=lane&15 (n), row=quad*4+reg (m); bf16 stores
  const float* bias = (ns < 2) ? bq : bv;
  ushort* outp = (ns < 2) ? q_out : v_out;
  ushort* posp = (ns < 2) ? pos_q : pos_v;
  const int wbase = (ns & 1) * 128;
  #pragma unroll
  for (int j = 0; j < 4; j++) {
    const int colq = wbase + wn * 64 + j * 16 + fr;   // 0..255
    const int h = colq >> 6, d = colq & 63;
    const float bj = bias[colq];
    #pragma unroll
    for (int i = 0; i < 2; i++) {
      const int mb = m0 + wm * 32 + i * 16 + quad * 4;
      #pragma unroll
      for (int r = 0; r < 4; r++) {
        const int m = mb + r;
        if (m < MROWS) {
          int b = m / TPC, tp = m - b * TPC;
          outp[(((size_t)(b * 4 + h)) * TPC + tp) * 64 + d] =
              (ushort)bfr(acc[i][j][r] + bj);
        } else if (m < MTOT) {
          posp[(m - MROWS) * 256 + colq] = (ushort)bfr(acc[i][j][r]);
        }
      }
    }
  }
}

// ---------------------------------------------------------------------------
// Pass 3: windowed attention. bf16 k/v/pos in ([B][H][TPC][64] layout ->
// contiguous 78-row slab per block), converted to fp32 once at LDS staging.
// Block = (b, h, 64-t tile); thread = (t_local, quarter of DH); 2-step
// 4-lane shuffle for the dot. fp32 output. ~25 MB traffic, near BW floor.
__global__ __launch_bounds__(256) void win_attn4(
    const ushort* __restrict__ q_out, const ushort* __restrict__ v_out,
    const ushort* __restrict__ pos_q, const ushort* __restrict__ pos_v,
    float* __restrict__ out) {
  __shared__ __align__(16) float ks[78][68];
  __shared__ __align__(16) float vs[78][68];
  __shared__ __align__(16) float pq[15][68];
  __shared__ __align__(16) float pv[15][68];
  const int tid = threadIdx.x;
  const int bh = blockIdx.x >> 6, tile = blockIdx.x & 63;
  const int b = bh >> 2, h = bh & 3;
  const int t0 = tile * 64;

  const size_t slab = (((size_t)(b * 4 + h)) * TPC + t0) * 64;
  for (int idx = tid; idx < 624; idx += 256) {
    int row = idx >> 3, c8 = (idx & 7) * 8;
    uint4 kc = *(const uint4*)(q_out + slab + idx * 8);
    ks[row][c8 + 0] = bflo(kc.x); ks[row][c8 + 1] = bfhi(kc.x);
    ks[row][c8 + 2] = bflo(kc.y); ks[row][c8 + 3] = bfhi(kc.y);
    ks[row][c8 + 4] = bflo(kc.z); ks[row][c8 + 5] = bfhi(kc.z);
    ks[row][c8 + 6] = bflo(kc.w); ks[row][c8 + 7] = bfhi(kc.w);
    uint4 vc = *(const uint4*)(v_out + slab + idx * 8);
    vs[row][c8 + 0] = bflo(vc.x); vs[row][c8 + 1] = bfhi(vc.x);
    vs[row][c8 + 2] = bflo(vc.y); vs[row][c8 + 3] = bfhi(vc.y);
    vs[row][c8 + 4] = bflo(vc.z); vs[row][c8 + 5] = bfhi(vc.z);
    vs[row][c8 + 6] = bflo(vc.w); vs[row][c8 + 7] = bfhi(vc.w);
  }
  if (tid < 120) {
    int row = tid >> 3, c8 = (tid & 7) * 8;
    uint4 qc = *(const uint4*)(pos_q + row * 256 + h * 64 + c8);
    pq[row][c8 + 0] = bflo(qc.x); pq[row][c8 + 1] = bfhi(qc.x);
    pq[row][c8 + 2] = bflo(qc.y); pq[row][c8 + 3] = bfhi(qc.y);
    pq[row][c8 + 4] = bflo(qc.z); pq[row][c8 + 5] = bfhi(qc.z);
    pq[row][c8 + 6] = bflo(qc.w); pq[row][c8 + 7] = bfhi(qc.w);
    uint4 vc = *(const uint4*)(pos_v + row * 256 + h * 64 + c8);
    pv[row][c8 + 0] = bflo(vc.x); pv[row][c8 + 1] = bfhi(vc.x);
    pv[row][c8 + 2] = bflo(vc.y); pv[row][c8 + 3] = bfhi(vc.y);
    pv[row][c8 + 4] = bflo(vc.z); pv[row][c8 + 5] = bfhi(vc.z);
    pv[row][c8 + 6] = bflo(vc.w); pv[row][c8 + 7] = bfhi(vc.w);
  }
  __syncthreads();

  const int tl = tid >> 2, qtr = tid & 3, d0 = qtr * 16;
  float4 qv[4];
  #pragma unroll
  for (int c = 0; c < 4; c++) qv[c] = *(float4*)&ks[tl + 7][d0 + c * 4];
  float4 ctx[4];
  #pragma unroll
  for (int c = 0; c < 4; c++) ctx[c] = make_float4(0.f, 0.f, 0.f, 0.f);

  #pragma unroll
  for (int w = 0; w < 15; w++) {
    float p = 0.f;
    #pragma unroll
    for (int c = 0; c < 4; c++) {
      float4 kk = *(float4*)&ks[tl + w][d0 + c * 4];
      float4 pp = *(float4*)&pq[w][d0 + c * 4];
      p += qv[c].x * (kk.x + pp.x) + qv[c].y * (kk.y + pp.y) +
           qv[c].z * (kk.z + pp.z) + qv[c].w * (kk.w + pp.w);
    }
    p += __shfl_xor(p, 1, 64);
    p += __shfl_xor(p, 2, 64);
    #pragma unroll
    for (int c = 0; c < 4; c++) {
      float4 vv = *(float4*)&vs[tl + w][d0 + c * 4];
      float4 pp = *(float4*)&pv[w][d0 + c * 4];
      ctx[c].x += p * (vv.x + pp.x);
      ctx[c].y += p * (vv.y + pp.y);
      ctx[c].z += p * (vv.z + pp.z);
      ctx[c].w += p * (vv.w + pp.w);
    }
  }
  size_t oo = ((size_t)(b * 4096 + t0 + tl)) * 256 + h * 64 + d0;
  #pragma unroll
  for (int c = 0; c < 4; c++) *(float4*)(out + oo + c * 4) = ctx[c];
}

// ---------------------------------------------------------------------------
extern "C" void kernel_launch(void* const* d_in, const int* in_sizes, int n_in,
                              void* d_out, int out_size, void* d_ws,
                              size_t ws_size, hipStream_t stream) {
  const float* inp = (const float*)d_in[0];
  const float* Wq  = (const float*)d_in[1];
  const float* bq  = (const float*)d_in[2];
  const float* Wv  = (const float*)d_in[3];
  const float* bv  = (const float*)d_in[4];
  const float* pos = (const float*)d_in[5];
  float* out = (float*)d_out;

  // ws layout (bytes): Wbf 786,432 | q_out 4,208,640 | v_out 4,208,640 |
  // pos_q 7,680 | pos_v 7,680  -> ~9.2 MB
  char* ws = (char*)d_ws;
  ushort* Wbf   = (ushort*)ws;
  ushort* q_out = (ushort*)(ws + 786432);     // [B][H][TPC][64] bf16
  ushort* v_out = (ushort*)(ws + 4995072);
  ushort* pos_q = (ushort*)(ws + 9203712);    // [15][256] bf16
  ushort* pos_v = (ushort*)(ws + 9211392);

  hipLaunchKernelGGL(cast_w, dim3(192), dim3(256), 0, stream, Wq, Wv, Wbf);
  hipLaunchKernelGGL(gemm_bf16, dim3(520), dim3(256), 0, stream,
                     inp, pos, Wbf, bq, bv, q_out, v_out, pos_q, pos_v);
  hipLaunchKernelGGL(win_attn4, dim3(2 * 4 * 64), dim3(256), 0, stream,
                     q_out, v_out, pos_q, pos_v, out);
}

// Round 4
// 107.713 us; speedup vs baseline: 1.2384x; 1.2384x over previous
//
#include <hip/hip_runtime.h>

// MyAttention: B=2, T=4096, D=768, DO=256, H=4, DH=64, W2=15
// Structure (R10 = revert to R8, best measured 107.9us):
//   cast_w -> gemm_bf16 (A-cast fused via cooperative reg->LDS staging) ->
//   win_attn4.
// R9 lesson: per-lane A fragment loads direct from global (16 rows x 3KB
// stride per wave instruction) are latency-poison: gemm 50us, MfmaUtil 4.5%,
// 84 VGPR (compiler refused to pipeline the scattered loads). Cooperative
// 1KB/wave contiguous staging through LDS is the right structure; its LDS
// traffic is hidden under MFMA.
// R8: A-cast fused (fp32 A read once, L2-resident via XCD chunk swizzle);
// Abf round trip eliminated. R7: 2-phase double-buffered pipeline, single
// syncthreads per K-step. Harness floor: 2x43us poison fills are invariant.
#define TPC   4110            // T + 14 (padded seq)
#define MROWS 8220            // B * TPC
#define MTOT  8235            // + 15 pos rows
#define MPAD  8320            // 130 * 64
#define KD    768

typedef __attribute__((ext_vector_type(8))) short short8;
typedef __attribute__((ext_vector_type(4))) float f32x4;

#define LOAD_LDS16(gp, lp)                                                   \
  __builtin_amdgcn_global_load_lds(                                          \
      (const __attribute__((address_space(1))) void*)(gp),                   \
      (__attribute__((address_space(3))) void*)(lp), 16, 0, 0)

__device__ inline unsigned bfr(float x) {
  unsigned u = __float_as_uint(x);
  return (u + 0x7FFFu + ((u >> 16) & 1u)) >> 16;   // RNE fp32->bf16
}
__device__ inline unsigned pack2(float a, float b) {
  return bfr(a) | (bfr(b) << 16);
}
__device__ inline float bflo(unsigned u) { return __uint_as_float(u << 16); }
__device__ inline float bfhi(unsigned u) { return __uint_as_float(u & 0xffff0000u); }

// ---------------------------------------------------------------------------
// Pass 1: cast W only ([Wq;Wv], 512 x 768) to bf16. 192 blocks, ~0.4 us.
__global__ __launch_bounds__(256) void cast_w(
    const float* __restrict__ Wq, const float* __restrict__ Wv,
    ushort* __restrict__ Wbf) {
  int gid = blockIdx.x * 256 + threadIdx.x;      // grid = 512*96/256 exact
  int row = gid / 96, c = (gid - row * 96) * 8;
  const float* src = (row < 256) ? Wq + (size_t)row * KD + c
                                 : Wv + (size_t)(row - 256) * KD + c;
  float4 f0 = *(const float4*)src;
  float4 f1 = *(const float4*)(src + 4);
  uint4 o;
  o.x = pack2(f0.x, f0.y); o.y = pack2(f0.z, f0.w);
  o.z = pack2(f1.x, f1.y); o.w = pack2(f1.z, f1.w);
  *(uint4*)(Wbf + (size_t)row * KD + c) = o;
}

// ---------------------------------------------------------------------------
// Pass 2: C[MPAD][512] = A @ Wbf^T, A cast fp32->bf16 in-flight.
// bf16 MFMA 16x16x32, 64(m) x 128(n) tiles, BK=64, 520 blocks.
// A: cooperatively reg-staged from fp32 inputs (8 threads x 32B contiguous
//    per row -> full coalescing; zero-pad + pos rows by per-row predication),
//    converted + ds_write_b128 into the idle LDS buffer while MFMA runs on
//    the other -- load issue at body top, first reg use after COMPUTE, so
//    HBM/L2 latency hides under the MFMAs.
// B: global_load_lds width-16 from Wbf (dbuf).
// k-chunks XOR-swizzled by (row&7) inside each 128B row (both the A LDS
// writes and the B global sources), so fragment ds_read_b128 stays at the
// wave64 bank minimum. ds_write pattern is 1024B contiguous per wave: free.
// Grid flattened 1D + bijective XCD-chunk swizzle (520 = 8*65): each XCD gets
// ~16 consecutive m-tiles x 4 n-strips, so each m-tile's 4 fp32-A readers are
// co-resident on one L2 (~3.3MB A + 0.8MB B ~ 4MB/XCD).
// bf16 outputs in attention layout q/v [B][H][TPC][64]; pos -> [15][256].
__global__ __launch_bounds__(256) void gemm_bf16(
    const float* __restrict__ inp, const float* __restrict__ pos,
    const ushort* __restrict__ Wbf,
    const float* __restrict__ bq, const float* __restrict__ bv,
    ushort* __restrict__ q_out, ushort* __restrict__ v_out,
    ushort* __restrict__ pos_q, ushort* __restrict__ pos_v) {
  __shared__ ushort Al[2][64 * 64];    // 2 x 8 KB
  __shared__ ushort Bl[2][128 * 64];   // 2 x 16 KB
  const int tid = threadIdx.x;
  const int wave = tid >> 6, lane = tid & 63;
  const int lin = blockIdx.x;
  const int wg = (lin & 7) * 65 + (lin >> 3);
  const int ns = wg & 3;                // 0..3 (0-1 -> q, 2-3 -> v)
  const int m0 = (wg >> 2) * 64;        // 0..129 m-tiles
  const int wm = wave & 1, wn = wave >> 1;
  const int fr = lane & 15, quad = lane >> 4;

  // A staging map: chunk c = i*256+tid -> row = c>>3, LDS slot kq = c&7,
  // global source = logical k-chunk (kq ^ (row&7))  [read-side un-swizzles].
  // Per-row source predication replicates the zero-pad logic.
  const float* agf[2];
  int aoff[2];                          // LDS ushort offset for the chunk
  #pragma unroll
  for (int i = 0; i < 2; i++) {
    int c = i * 256 + tid, row = c >> 3, kq = c & 7;
    int m = m0 + row;
    aoff[i] = c * 8;                    // == row*64 + kq*8
    const float* s = nullptr;
    if (m < MROWS) {
      int bb = (m >= TPC) ? 1 : 0;
      int t = m - bb * TPC - 7;
      if (t >= 0 && t < 4096)
        s = inp + ((size_t)bb * 4096 + t) * KD + ((kq ^ (row & 7)) * 8);
    } else if (m < MTOT) {
      s = pos + (size_t)(m - MROWS) * KD + ((kq ^ (row & 7)) * 8);
    }
    agf[i] = s;
  }
  const ushort* bg[4];
  #pragma unroll
  for (int i = 0; i < 4; i++) {
    int c = i * 256 + tid, row = c >> 3, kq = c & 7;
    bg[i] = Wbf + (size_t)(ns * 128 + row) * KD + ((kq ^ (row & 7)) * 8);
  }

  f32x4 acc[2][4];
  #pragma unroll
  for (int i = 0; i < 2; i++)
    #pragma unroll
    for (int j = 0; j < 4; j++) acc[i][j] = 0.0f;

  float4 fa[2][2];                      // in-flight A regs (8 fp32 per chunk)

#define STAGE_A_LOAD(k0)                                                     \
  do {                                                                       \
    _Pragma("unroll")                                                        \
    for (int i = 0; i < 2; i++) {                                            \
      if (agf[i]) {                                                          \
        fa[i][0] = *(const float4*)(agf[i] + (k0));                          \
        fa[i][1] = *(const float4*)(agf[i] + (k0) + 4);                      \
      } else {                                                               \
        fa[i][0] = make_float4(0.f, 0.f, 0.f, 0.f);                         \
        fa[i][1] = make_float4(0.f, 0.f, 0.f, 0.f);                         \
      }                                                                      \
    }                                                                        \
  } while (0)

#define STAGE_A_WRITE(bsel)                                                  \
  do {                                                                       \
    _Pragma("unroll")                                                        \
    for (int i = 0; i < 2; i++) {                                            \
      uint4 o;                                                               \
      o.x = pack2(fa[i][0].x, fa[i][0].y);                                   \
      o.y = pack2(fa[i][0].z, fa[i][0].w);                                   \
      o.z = pack2(fa[i][1].x, fa[i][1].y);                                   \
      o.w = pack2(fa[i][1].z, fa[i][1].w);                                   \
      *(uint4*)(&Al[bsel][0] + aoff[i]) = o;                                 \
    }                                                                        \
  } while (0)

#define STAGE_B(bsel, k0)                                                    \
  do {                                                                       \
    _Pragma("unroll")                                                        \
    for (int i = 0; i < 4; i++)                                              \
      LOAD_LDS16(bg[i] + (k0), &Bl[bsel][0] + (i * 256 + wave * 64) * 8);    \
  } while (0)

#define COMPUTE(bsel)                                                        \
  do {                                                                       \
    short8 afr[2][2], bfrag[2][4];                                           \
    _Pragma("unroll")                                                        \
    for (int ks = 0; ks < 2; ks++) {                                         \
      const int e = ((ks * 4 + quad) ^ (fr & 7)) * 8;   /* un-swizzle */     \
      _Pragma("unroll")                                                      \
      for (int i = 0; i < 2; i++)                                            \
        afr[ks][i] =                                                         \
            *(const short8*)(&Al[bsel][0] + (wm * 32 + i * 16 + fr) * 64 + e);\
      _Pragma("unroll")                                                      \
      for (int j = 0; j < 4; j++)                                            \
        bfrag[ks][j] =                                                       \
            *(const short8*)(&Bl[bsel][0] + (wn * 64 + j * 16 + fr) * 64 + e);\
    }                                                                        \
    _Pragma("unroll")                                                        \
    for (int ks = 0; ks < 2; ks++)                                           \
      _Pragma("unroll")                                                      \
      for (int i = 0; i < 2; i++)                                            \
        _Pragma("unroll")                                                    \
        for (int j = 0; j < 4; j++)                                          \
          acc[i][j] = __builtin_amdgcn_mfma_f32_16x16x32_bf16(               \
              afr[ks][i], bfrag[ks][j], acc[i][j], 0, 0, 0);                 \
  } while (0)

  // prologue: fill buf0 (k=0), drain.
  STAGE_A_LOAD(0);
  STAGE_B(0, 0);
  STAGE_A_WRITE(0);
  __syncthreads();
  // steady state: 12 K-steps, 2 per body (compile-time buffer index).
  // Body: issue next A-loads + B-gload_lds; MFMA current buffer (latency
  // hides here); convert+write A into idle buffer; barrier (drains vmcnt).
  #pragma unroll 1
  for (int k0 = 0; k0 < 640; k0 += 128) {
    STAGE_A_LOAD(k0 + 64);
    STAGE_B(1, k0 + 64);
    COMPUTE(0);
    STAGE_A_WRITE(1);
    __syncthreads();
    STAGE_A_LOAD(k0 + 128);
    STAGE_B(0, k0 + 128);
    COMPUTE(1);
    STAGE_A_WRITE(0);
    __syncthreads();
  }
  STAGE_A_LOAD(704);
  STAGE_B(1, 704);
  COMPUTE(0);                   // k = 640
  STAGE_A_WRITE(1);
  __syncthreads();
  COMPUTE(1);                   // k = 704 (no further stage)

#undef STAGE_A_LOAD
#undef STAGE_A_WRITE
#undef STAGE_B
#undef COMPUTE

  // epilogue: C/D layout col=lane&15 (n), row=quad*4+reg (m); bf16 stores
  const float* bias = (ns < 2) ? bq : bv;
  ushort* outp = (ns < 2) ? q_out : v_out;
  ushort* posp = (ns < 2) ? pos_q : pos_v;
  const int wbase = (ns & 1) * 128;
  #pragma unroll
  for (int j = 0; j < 4; j++) {
    const int colq = wbase + wn * 64 + j * 16 + fr;   // 0..255
    const int h = colq >> 6, d = colq & 63;
    const float bj = bias[colq];
    #pragma unroll
    for (int i = 0; i < 2; i++) {
      const int mb = m0 + wm * 32 + i * 16 + quad * 4;
      #pragma unroll
      for (int r = 0; r < 4; r++) {
        const int m = mb + r;
        if (m < MROWS) {
          int b = m / TPC, tp = m - b * TPC;
          outp[(((size_t)(b * 4 + h)) * TPC + tp) * 64 + d] =
              (ushort)bfr(acc[i][j][r] + bj);
        } else if (m < MTOT) {
          posp[(m - MROWS) * 256 + colq] = (ushort)bfr(acc[i][j][r]);
        }
      }
    }
  }
}

// ---------------------------------------------------------------------------
// Pass 3: windowed attention. bf16 k/v/pos in ([B][H][TPC][64] layout ->
// contiguous 78-row slab per block), converted to fp32 once at LDS staging.
// Block = (b, h, 64-t tile); thread = (t_local, quarter of DH); 2-step
// 4-lane shuffle for the dot. fp32 output. ~21 MB traffic, near BW floor.
__global__ __launch_bounds__(256) void win_attn4(
    const ushort* __restrict__ q_out, const ushort* __restrict__ v_out,
    const ushort* __restrict__ pos_q, const ushort* __restrict__ pos_v,
    float* __restrict__ out) {
  __shared__ __align__(16) float ks[78][68];
  __shared__ __align__(16) float vs[78][68];
  __shared__ __align__(16) float pq[15][68];
  __shared__ __align__(16) float pv[15][68];
  const int tid = threadIdx.x;
  const int bh = blockIdx.x >> 6, tile = blockIdx.x & 63;
  const int b = bh >> 2, h = bh & 3;
  const int t0 = tile * 64;

  const size_t slab = (((size_t)(b * 4 + h)) * TPC + t0) * 64;
  for (int idx = tid; idx < 624; idx += 256) {
    int row = idx >> 3, c8 = (idx & 7) * 8;
    uint4 kc = *(const uint4*)(q_out + slab + idx * 8);
    ks[row][c8 + 0] = bflo(kc.x); ks[row][c8 + 1] = bfhi(kc.x);
    ks[row][c8 + 2] = bflo(kc.y); ks[row][c8 + 3] = bfhi(kc.y);
    ks[row][c8 + 4] = bflo(kc.z); ks[row][c8 + 5] = bfhi(kc.z);
    ks[row][c8 + 6] = bflo(kc.w); ks[row][c8 + 7] = bfhi(kc.w);
    uint4 vc = *(const uint4*)(v_out + slab + idx * 8);
    vs[row][c8 + 0] = bflo(vc.x); vs[row][c8 + 1] = bfhi(vc.x);
    vs[row][c8 + 2] = bflo(vc.y); vs[row][c8 + 3] = bfhi(vc.y);
    vs[row][c8 + 4] = bflo(vc.z); vs[row][c8 + 5] = bfhi(vc.z);
    vs[row][c8 + 6] = bflo(vc.w); vs[row][c8 + 7] = bfhi(vc.w);
  }
  if (tid < 120) {
    int row = tid >> 3, c8 = (tid & 7) * 8;
    uint4 qc = *(const uint4*)(pos_q + row * 256 + h * 64 + c8);
    pq[row][c8 + 0] = bflo(qc.x); pq[row][c8 + 1] = bfhi(qc.x);
    pq[row][c8 + 2] = bflo(qc.y); pq[row][c8 + 3] = bfhi(qc.y);
    pq[row][c8 + 4] = bflo(qc.z); pq[row][c8 + 5] = bfhi(qc.z);
    pq[row][c8 + 6] = bflo(qc.w); pq[row][c8 + 7] = bfhi(qc.w);
    uint4 vc = *(const uint4*)(pos_v + row * 256 + h * 64 + c8);
    pv[row][c8 + 0] = bflo(vc.x); pv[row][c8 + 1] = bfhi(vc.x);
    pv[row][c8 + 2] = bflo(vc.y); pv[row][c8 + 3] = bfhi(vc.y);
    pv[row][c8 + 4] = bflo(vc.z); pv[row][c8 + 5] = bfhi(vc.z);
    pv[row][c8 + 6] = bflo(vc.w); pv[row][c8 + 7] = bfhi(vc.w);
  }
  __syncthreads();

  const int tl = tid >> 2, qtr = tid & 3, d0 = qtr * 16;
  float4 qv[4];
  #pragma unroll
  for (int c = 0; c < 4; c++) qv[c] = *(float4*)&ks[tl + 7][d0 + c * 4];
  float4 ctx[4];
  #pragma unroll
  for (int c = 0; c < 4; c++) ctx[c] = make_float4(0.f, 0.f, 0.f, 0.f);

  #pragma unroll
  for (int w = 0; w < 15; w++) {
    float p = 0.f;
    #pragma unroll
    for (int c = 0; c < 4; c++) {
      float4 kk = *(float4*)&ks[tl + w][d0 + c * 4];
      float4 pp = *(float4*)&pq[w][d0 + c * 4];
      p += qv[c].x * (kk.x + pp.x) + qv[c].y * (kk.y + pp.y) +
           qv[c].z * (kk.z + pp.z) + qv[c].w * (kk.w + pp.w);
    }
    p += __shfl_xor(p, 1, 64);
    p += __shfl_xor(p, 2, 64);
    #pragma unroll
    for (int c = 0; c < 4; c++) {
      float4 vv = *(float4*)&vs[tl + w][d0 + c * 4];
      float4 pp = *(float4*)&pv[w][d0 + c * 4];
      ctx[c].x += p * (vv.x + pp.x);
      ctx[c].y += p * (vv.y + pp.y);
      ctx[c].z += p * (vv.z + pp.z);
      ctx[c].w += p * (vv.w + pp.w);
    }
  }
  size_t oo = ((size_t)(b * 4096 + t0 + tl)) * 256 + h * 64 + d0;
  #pragma unroll
  for (int c = 0; c < 4; c++) *(float4*)(out + oo + c * 4) = ctx[c];
}

// ---------------------------------------------------------------------------
extern "C" void kernel_launch(void* const* d_in, const int* in_sizes, int n_in,
                              void* d_out, int out_size, void* d_ws,
                              size_t ws_size, hipStream_t stream) {
  const float* inp = (const float*)d_in[0];
  const float* Wq  = (const float*)d_in[1];
  const float* bq  = (const float*)d_in[2];
  const float* Wv  = (const float*)d_in[3];
  const float* bv  = (const float*)d_in[4];
  const float* pos = (const float*)d_in[5];
  float* out = (float*)d_out;

  // ws layout (bytes): Wbf 786,432 | q_out 4,208,640 | v_out 4,208,640 |
  // pos_q 7,680 | pos_v 7,680  -> ~9.2 MB
  char* ws = (char*)d_ws;
  ushort* Wbf   = (ushort*)ws;
  ushort* q_out = (ushort*)(ws + 786432);     // [B][H][TPC][64] bf16
  ushort* v_out = (ushort*)(ws + 4995072);
  ushort* pos_q = (ushort*)(ws + 9203712);    // [15][256] bf16
  ushort* pos_v = (ushort*)(ws + 9211392);

  hipLaunchKernelGGL(cast_w, dim3(192), dim3(256), 0, stream, Wq, Wv, Wbf);
  hipLaunchKernelGGL(gemm_bf16, dim3(520), dim3(256), 0, stream,
                     inp, pos, Wbf, bq, bv, q_out, v_out, pos_q, pos_v);
  hipLaunchKernelGGL(win_attn4, dim3(2 * 4 * 64), dim3(256), 0, stream,
                     q_out, v_out, pos_q, pos_v, out);
}